// Round 1
// baseline (600.672 us; speedup 1.0000x reference)
//
#include <hip/hip_runtime.h>

// GaussianTorchBlur: per-sample truncated gaussian separable blur, reflect pad.
// x: (64,3,512,512) f32; sigmas: (100,) f32; steps: (64,) i32; r_max=64 (static).
// Plan: weights kernel -> horizontal pass (LDS row, register-blocked) -> vertical
// pass (coalesced float2, register-blocked). Intermediate (192MB) lives in d_ws.

#define KP 160           // padded per-sample weight array length
#define WOFF 80          // weight index = WOFF + k, k in [-80, 80)
#define WS_MID_OFF 16384 // floats (64 KiB) reserved for weights at front of ws

__global__ void gw_kernel(const float* __restrict__ sigmas,
                          const int* __restrict__ steps,
                          float* __restrict__ wout) {
  int b = blockIdx.x, tid = threadIdx.x;
  float sig = sigmas[steps[b]];
  int r = (int)(4.0f * sig + 0.5f);   // matches (4*sigma+0.5).astype(int32)
  int k = tid - WOFF;
  int ak = k < 0 ? -k : k;
  float w = 0.0f;
  if (tid < KP && ak <= r) {
    float t = (float)k / sig;
    w = expf(-0.5f * t * t);
  }
  __shared__ float sd[256];
  sd[tid] = w;
  __syncthreads();
  for (int s = 128; s > 0; s >>= 1) {
    if (tid < s) sd[tid] += sd[tid + s];
    __syncthreads();
  }
  if (tid < KP) wout[b * KP + tid] = w / sd[0];
}

// Horizontal pass: 4 rows per block (1 wave each), each lane produces 8
// consecutive x outputs via sliding 15-reg window over chunks of 8 taps.
__global__ __launch_bounds__(256) void hblur_kernel(
    const float* __restrict__ x, const float* __restrict__ wall,
    const float* __restrict__ sigmas, const int* __restrict__ steps,
    float* __restrict__ mid) {
  __shared__ float rowbuf[4][684];  // 656 logical + pad-per-32 swizzle
  __shared__ float wbuf[KP];
  const int tid = threadIdx.x;
  const int rl = tid >> 6, lane = tid & 63;
  const int row0 = blockIdx.x << 2;      // 4 rows per block, never crosses (b,c)
  const int b = row0 / 1536;             // 3*512 rows per sample
  if (tid < KP) wbuf[tid] = wall[b * KP + tid];
  const int rid = row0 + rl;
  const float* xrow = x + (size_t)rid * 512;
  // buf[i] = xrow[reflect(i-72)] for i in [8,648); zeros outside
  for (int i = lane; i < 656; i += 64) {
    int xc = i - 72;
    float v = 0.0f;
    if (xc >= -64 && xc < 576) {
      int xs = xc < 0 ? -xc : (xc >= 512 ? 1022 - xc : xc);
      v = xrow[xs];
    }
    rowbuf[rl][i + (i >> 5)] = v;
  }
  __syncthreads();
  const float sig = sigmas[steps[b]];
  const int r = (int)(4.0f * sig + 0.5f);
  const int NT = (2 * r + 8) >> 3;       // ceil((2r+1)/8) chunks of 8 taps
  const int x0 = lane << 3;
  float acc[8];
#pragma unroll
  for (int j = 0; j < 8; ++j) acc[j] = 0.0f;
  int kb = -r;
  const int pb = x0 + 72;
  float D[15];
#pragma unroll
  for (int i = 0; i < 15; ++i) {
    int p = pb + kb + i;
    D[i] = rowbuf[rl][p + (p >> 5)];
  }
  for (int c = 0; c < NT; ++c, kb += 8) {
#pragma unroll
    for (int dk = 0; dk < 8; ++dk) {
      float wv = wbuf[WOFF + kb + dk];   // uniform -> LDS broadcast
#pragma unroll
      for (int j = 0; j < 8; ++j) acc[j] = fmaf(wv, D[dk + j], acc[j]);
    }
    if (c + 1 < NT) {
#pragma unroll
      for (int i = 0; i < 7; ++i) D[i] = D[i + 8];
#pragma unroll
      for (int i = 0; i < 8; ++i) {
        int p = pb + kb + 15 + i;
        D[7 + i] = rowbuf[rl][p + (p >> 5)];
      }
    }
  }
  float4* orow = (float4*)(mid + (size_t)rid * 512 + x0);
  orow[0] = make_float4(acc[0], acc[1], acc[2], acc[3]);
  orow[1] = make_float4(acc[4], acc[5], acc[6], acc[7]);
}

// Vertical pass: block covers full 512-wide row span (256 thr x float2),
// 8 output rows per thread, same chunked sliding window; y-reflect on the fly.
__global__ __launch_bounds__(256) void vblur_kernel(
    const float* __restrict__ mid, const float* __restrict__ wall,
    const float* __restrict__ sigmas, const int* __restrict__ steps,
    float* __restrict__ out) {
  __shared__ float wbuf[KP];
  const int tid = threadIdx.x;
  const int bc = blockIdx.x >> 6;        // b*3 + c
  const int y0 = (blockIdx.x & 63) << 3;
  const int b = bc / 3;
  if (tid < KP) wbuf[tid] = wall[b * KP + tid];
  __syncthreads();
  const float sig = sigmas[steps[b]];
  const int r = (int)(4.0f * sig + 0.5f);
  const int NT = (2 * r + 8) >> 3;
  const float* base = mid + (size_t)bc * 262144 + (tid << 1);
  float2 acc[8];
#pragma unroll
  for (int j = 0; j < 8; ++j) acc[j] = make_float2(0.0f, 0.0f);
  int kb = -r;
  float2 D[15];
#pragma unroll
  for (int i = 0; i < 15; ++i) {
    int ry = y0 + kb + i;
    ry = ry < 0 ? -ry : (ry > 511 ? 1022 - ry : ry);
    D[i] = *(const float2*)(base + (size_t)ry * 512);
  }
  for (int c = 0; c < NT; ++c, kb += 8) {
#pragma unroll
    for (int dk = 0; dk < 8; ++dk) {
      float wv = wbuf[WOFF + kb + dk];
#pragma unroll
      for (int j = 0; j < 8; ++j) {
        acc[j].x = fmaf(wv, D[dk + j].x, acc[j].x);
        acc[j].y = fmaf(wv, D[dk + j].y, acc[j].y);
      }
    }
    if (c + 1 < NT) {
#pragma unroll
      for (int i = 0; i < 7; ++i) D[i] = D[i + 8];
#pragma unroll
      for (int i = 0; i < 8; ++i) {
        int ry = y0 + kb + 15 + i;
        ry = ry < 0 ? -ry : (ry > 511 ? 1022 - ry : ry);
        D[7 + i] = *(const float2*)(base + (size_t)ry * 512);
      }
    }
  }
  float* obase = out + (size_t)bc * 262144 + (tid << 1);
#pragma unroll
  for (int j = 0; j < 8; ++j)
    *(float2*)(obase + (size_t)(y0 + j) * 512) = acc[j];
}

extern "C" void kernel_launch(void* const* d_in, const int* in_sizes, int n_in,
                              void* d_out, int out_size, void* d_ws, size_t ws_size,
                              hipStream_t stream) {
  const float* x      = (const float*)d_in[0];
  const float* sigmas = (const float*)d_in[1];
  const int*   steps  = (const int*)d_in[2];
  float* out = (float*)d_out;
  float* wg  = (float*)d_ws;              // 64*KP weights
  float* mid = wg + WS_MID_OFF;           // 192 MiB intermediate
  gw_kernel<<<64, 256, 0, stream>>>(sigmas, steps, wg);
  hblur_kernel<<<24576, 256, 0, stream>>>(x, wg, sigmas, steps, mid);
  vblur_kernel<<<12288, 256, 0, stream>>>(mid, wg, sigmas, steps, out);
}